// Round 11
// baseline (456.744 us; speedup 1.0000x reference)
//
#include <hip/hip_runtime.h>
#include <stdint.h>

#define NM 128   // matrix dim / electrons
#define NT 512   // 8 waves; TWO matrices per wave (R11).
                 // Wave w owns M1-groups {w, w+8} in sv[0..15] and
                 // M2-groups {w^1, (w^1)+8} in sv[16..31].
                 // Per round: two independent factor chains in different
                 // waves on different SIMDs (rd+1 vs (rd+1)^1), and every
                 // wave has ~2x apply work to fill the factor windows.
                 // lane l owns rows l, l+64. Per-matrix math identical to
                 // R10 (297 us dispatch verified) -> bit-identical output.

typedef float v2f __attribute__((ext_vector_type(2)));

__device__ __forceinline__ float readlane_f(float v, int lane) {
    return __int_as_float(__builtin_amdgcn_readlane(__float_as_int(v), lane));
}

// Full 64-lane unsigned max via DPP (VALU pipe); result valid in lane 63.
__device__ __forceinline__ unsigned wave_max_dpp(unsigned x) {
    int v = (int)x;
#define DPP_STEP(ctrl) \
    { int o = __builtin_amdgcn_update_dpp(0, v, ctrl, 0xf, 0xf, true); \
      v = ((unsigned)o > (unsigned)v) ? o : v; }
    DPP_STEP(0x111)  // row_shr:1
    DPP_STEP(0x112)  // row_shr:2
    DPP_STEP(0x114)  // row_shr:4
    DPP_STEP(0x118)  // row_shr:8
    DPP_STEP(0x142)  // row_bcast:15
    DPP_STEP(0x143)  // row_bcast:31
#undef DPP_STEP
    return (unsigned)v;
}

__device__ __forceinline__ unsigned pack_key(float v, int r) {
    // monotone in |v|; drop 6 mantissa LSBs to make room for the 7-bit row id
    return (((__float_as_uint(v) & 0x7fffffffu) >> 6) << 7) | (unsigned)r;
}

// max(ka,kb) over the wave, broadcast to all lanes (uniform result)
__device__ __forceinline__ unsigned argmax_bcast(unsigned ka, unsigned kb) {
    const unsigned m = wave_max_dpp(ka > kb ? ka : kb);
    return (unsigned)__builtin_amdgcn_readlane((int)m, 63);
}

// read pivot row p's element of a (row r0, row r1) register pair; p uniform
__device__ __forceinline__ float sel_readlane(v2f c, int p) {
    return (p < 64) ? readlane_f(c.x, p) : readlane_f(c.y, p - 64);
}

// apply one pivot (row p, NEGATED multipliers lmn) to cols sv[B..B+7]
template<int B>
__device__ __forceinline__ void apply8T(v2f (&sv)[32], int p, v2f lmn) {
    float u[8];
    if (p < 64) {
#pragma unroll
        for (int j = 0; j < 8; ++j) u[j] = readlane_f(sv[B + j].x, p);
#pragma unroll
        for (int j = 0; j < 8; ++j)
            sv[B + j] = __builtin_elementwise_fma((v2f){u[j], u[j]}, lmn, sv[B + j]);
    } else {
        const int q = p - 64;
#pragma unroll
        for (int j = 0; j < 8; ++j) u[j] = readlane_f(sv[B + j].y, q);
#pragma unroll
        for (int j = 0; j < 8; ++j)
            sv[B + j] = __builtin_elementwise_fma((v2f){u[j], u[j]}, lmn, sv[B + j]);
    }
}

// apply one pivot to 16 cols sv[B..B+15] under one uniform branch; u[8] reused
template<int B>
__device__ __forceinline__ void apply16T(v2f (&sv)[32], int p, v2f lmn) {
    float u[8];
    if (p < 64) {
#pragma unroll
        for (int j = 0; j < 8; ++j) u[j] = readlane_f(sv[B + j].x, p);
#pragma unroll
        for (int j = 0; j < 8; ++j)
            sv[B + j] = __builtin_elementwise_fma((v2f){u[j], u[j]}, lmn, sv[B + j]);
#pragma unroll
        for (int j = 0; j < 8; ++j) u[j] = readlane_f(sv[B + 8 + j].x, p);
#pragma unroll
        for (int j = 0; j < 8; ++j)
            sv[B + 8 + j] = __builtin_elementwise_fma((v2f){u[j], u[j]}, lmn, sv[B + 8 + j]);
    } else {
        const int q = p - 64;
#pragma unroll
        for (int j = 0; j < 8; ++j) u[j] = readlane_f(sv[B + j].y, q);
#pragma unroll
        for (int j = 0; j < 8; ++j)
            sv[B + j] = __builtin_elementwise_fma((v2f){u[j], u[j]}, lmn, sv[B + j]);
#pragma unroll
        for (int j = 0; j < 8; ++j) u[j] = readlane_f(sv[B + 8 + j].y, q);
#pragma unroll
        for (int j = 0; j < 8; ++j)
            sv[B + 8 + j] = __builtin_elementwise_fma((v2f){u[j], u[j]}, lmn, sv[B + 8 + j]);
    }
}

// factor 8 cols sv[B..B+7] in place, publishing NEGATED pre-multiplied +
// pre-zeroed multipliers, keys, exact pivots, elim ballots.
template<int B>
__device__ __forceinline__ void lookahead8(v2f (&sv)[32], bool& elim0, bool& elim1,
                                           int r0, int r1, int l, int g,
                                           float2 (*colvg)[64],
                                           unsigned* keysM, float* pivsM,
                                           ulonglong2* masksM) {
    const bool e0in = elim0, e1in = elim1;
    __builtin_amdgcn_s_setprio(1);   // convoy-critical wave: favor its issue
#pragma unroll
    for (int i = 0; i < 8; ++i) {
        const v2f c = sv[B + i];
        const unsigned key = argmax_bcast(elim0 ? 0u : pack_key(c.x, r0),
                                          elim1 ? 0u : pack_key(c.y, r1));
        const int pu = __builtin_amdgcn_readfirstlane((int)(key & 127u));
        const float piv = sel_readlane(c, pu);
        const float rcpn = -__builtin_amdgcn_rcpf(piv);   // sign folded here
        elim0 = elim0 || (r0 == pu);
        elim1 = elim1 || (r1 == pu);
        const v2f lmn = { elim0 ? 0.0f : c.x * rcpn,
                          elim1 ? 0.0f : c.y * rcpn };
        colvg[i][l] = make_float2(lmn.x, lmn.y);
        float u[8];
        if (pu < 64) {
#pragma unroll
            for (int m = i + 1; m < 8; ++m) u[m] = readlane_f(sv[B + m].x, pu);
        } else {
#pragma unroll
            for (int m = i + 1; m < 8; ++m) u[m] = readlane_f(sv[B + m].y, pu - 64);
        }
#pragma unroll
        for (int m = i + 1; m < 8; ++m)
            sv[B + m] = __builtin_elementwise_fma((v2f){u[m], u[m]}, lmn, sv[B + m]);
        if (l == 0) { keysM[8 * g + i] = key; pivsM[8 * g + i] = piv; }
    }
    __builtin_amdgcn_s_setprio(0);
    const unsigned long long b0 = __ballot(elim0 && !e0in);
    const unsigned long long b1 = __ballot(elim1 && !e1in);
    if (l == 0) masksM[g] = make_ulonglong2(b0, b1);
}

__device__ __forceinline__ void decode_p(const unsigned* keysR, int (&p)[8]) {
    const uint4 ka = *(const uint4*)&keysR[0];
    const uint4 kb = *(const uint4*)&keysR[4];
    p[0] = __builtin_amdgcn_readfirstlane((int)(ka.x & 127u));
    p[1] = __builtin_amdgcn_readfirstlane((int)(ka.y & 127u));
    p[2] = __builtin_amdgcn_readfirstlane((int)(ka.z & 127u));
    p[3] = __builtin_amdgcn_readfirstlane((int)(ka.w & 127u));
    p[4] = __builtin_amdgcn_readfirstlane((int)(kb.x & 127u));
    p[5] = __builtin_amdgcn_readfirstlane((int)(kb.y & 127u));
    p[6] = __builtin_amdgcn_readfirstlane((int)(kb.z & 127u));
    p[7] = __builtin_amdgcn_readfirstlane((int)(kb.w & 127u));
}

// One round of one matrix for this wave. wOwn = this wave's chunk-A group id
// for this matrix; BASE = sv offset of this matrix's 16 columns.
// Schedule identical to R10: applyBoth while both chunks live; at
// rd==wOwn-1: applyLo -> factor(A) -> applyHi; afterwards Hi only; at
// rd==wOwn+7: applyHi -> factor(B); retired beyond.
template<int BASE>
__device__ __forceinline__ void matrixRound(v2f (&sv)[32], bool& e0, bool& e1,
                                            int rd, int wOwn, int r0, int r1, int l,
                                            float2 (*colvM)[8][64],
                                            unsigned* keysM, float* pivsM,
                                            ulonglong2* masksM) {
    if (rd > wOwn + 7) return;               // this matrix retired for us
    const ulonglong2 mk = masksM[rd];
    e0 = e0 || (((mk.x >> l) & 1ull) != 0);
    e1 = e1 || (((mk.y >> l) & 1ull) != 0);
    int p[8];
    decode_p(&keysM[8 * rd], p);
    const float2 (*cp)[64] = colvM[rd & 1];
    if (rd < wOwn - 1) {                     // both chunks live
#pragma unroll
        for (int i = 0; i < 8; ++i) {
            const float2 la = cp[i][l];
            apply16T<BASE>(sv, p[i], (v2f){la.x, la.y});
        }
    } else if (rd == wOwn - 1) {             // we publish next group: A first
        __builtin_amdgcn_s_setprio(1);
#pragma unroll
        for (int i = 0; i < 8; ++i) {
            const float2 la = cp[i][l];
            apply8T<BASE>(sv, p[i], (v2f){la.x, la.y});
        }
        lookahead8<BASE>(sv, e0, e1, r0, r1, l, rd + 1,
                         colvM[(rd + 1) & 1], keysM, pivsM, masksM);
#pragma unroll
        for (int i = 0; i < 8; ++i) {
            const float2 la = cp[i][l];
            apply8T<BASE + 8>(sv, p[i], (v2f){la.x, la.y});
        }
        __builtin_amdgcn_s_setprio(0);
    } else {                                 // chunk A retired: high half only
#pragma unroll
        for (int i = 0; i < 8; ++i) {
            const float2 la = cp[i][l];
            apply8T<BASE + 8>(sv, p[i], (v2f){la.x, la.y});
        }
        if (rd == wOwn + 7)                  // factor chunk B; retire after
            lookahead8<BASE + 8>(sv, e0, e1, r0, r1, l, rd + 1,
                                 colvM[(rd + 1) & 1], keysM, pivsM, masksM);
    }
}

__global__ __launch_bounds__(NT, 6)   // 6 waves/EU -> 3 blocks/CU = 6 matrices/CU
void slater_logdet(const float* __restrict__ rs,
                   const float* __restrict__ kpts,
                   const float* __restrict__ csw,
                   const float* __restrict__ ssw,
                   float* __restrict__ out) {
    __shared__ float2 colv[2][2][8][64];   // [matrix][parity][pivot][lane], NEGATED
    __shared__ unsigned keysF[2][NM];      // write-once pivot keys per matrix
    __shared__ float    pivsF[2][NM];      // write-once exact pivots
    __shared__ ulonglong2 masks[2][16];    // per-group new-pivot row ballots
    __shared__ float    redf[4];

    const int t  = threadIdx.x;
    const int bA = 2 * blockIdx.x;
    const int bB = 2 * blockIdx.x + 1;
    const int w  = t >> 6;    // wave id 0..7
    const int w2 = w ^ 1;     // M2 chunk-A group (different SIMD parity for factor)
    const int l  = t & 63;
    const int r0 = l, r1 = l + 64;

    v2f sv[32];   // [0..15]: M1 groups {w, w+8}; [16..31]: M2 groups {w2, w2+8}
    {
        // Switches are complementary binary (k_signs = +-1 always), so the
        // reference cw*cos(d) + sw*sin(-d) is exactly cos(d) when cw==1 and
        // exactly -sin(d) when sw==1: one trans op per element (R10, no-spill).
        const float* rsA = rs + (size_t)bA * NM * 3;
#pragma unroll
        for (int j = 0; j < 16; ++j) {
            const int m = (j < 8) ? (8 * w + j) : (64 + 8 * w + (j - 8));
            const float kx = kpts[m * 3 + 0], ky = kpts[m * 3 + 1], kz = kpts[m * 3 + 2];
            const float d0 = kx * rsA[r0 * 3] + ky * rsA[r0 * 3 + 1] + kz * rsA[r0 * 3 + 2];
            const float d1 = kx * rsA[r1 * 3] + ky * rsA[r1 * 3 + 1] + kz * rsA[r1 * 3 + 2];
            if (csw[m] != 0.0f) { sv[j].x = __cosf(d0);  sv[j].y = __cosf(d1); }
            else                { sv[j].x = -__sinf(d0); sv[j].y = -__sinf(d1); }
        }
        const float* rsB = rs + (size_t)bB * NM * 3;
#pragma unroll
        for (int j = 0; j < 16; ++j) {
            const int m = (j < 8) ? (8 * w2 + j) : (64 + 8 * w2 + (j - 8));
            const float kx = kpts[m * 3 + 0], ky = kpts[m * 3 + 1], kz = kpts[m * 3 + 2];
            const float d0 = kx * rsB[r0 * 3] + ky * rsB[r0 * 3 + 1] + kz * rsB[r0 * 3 + 2];
            const float d1 = kx * rsB[r1 * 3] + ky * rsB[r1 * 3 + 1] + kz * rsB[r1 * 3 + 2];
            if (csw[m] != 0.0f) { sv[16 + j].x = __cosf(d0);  sv[16 + j].y = __cosf(d1); }
            else                { sv[16 + j].x = -__sinf(d0); sv[16 + j].y = -__sinf(d1); }
        }
    }

    bool eA0 = false, eA1 = false, eB0 = false, eB1 = false;

    // ---- bootstrap: wave 0 factors M1-group 0; wave 1 factors M2-group 0 ----
    if (w == 0)
        lookahead8<0>(sv, eA0, eA1, r0, r1, l, 0, colv[0][0],
                      keysF[0], pivsF[0], masks[0]);
    if (w2 == 0)
        lookahead8<16>(sv, eB0, eB1, r0, r1, l, 0, colv[1][0],
                       keysF[1], pivsF[1], masks[1]);
    __syncthreads();

    // ---- main loop: 15 rounds; round rd applies group rd of each matrix.
    // Factor waves this round: M1 -> wave rd+1 (or rd-7), M2 -> that ^1:
    // always two distinct waves on different SIMDs. The matrix whose factor
    // we own goes first so its publish leaves the critical path early.
    for (int rd = 0; rd < 15; ++rd) {
        const bool fac2 = (rd == w2 - 1) || (rd == w2 + 7);
        if (fac2) {
            matrixRound<16>(sv, eB0, eB1, rd, w2, r0, r1, l,
                            colv[1], keysF[1], pivsF[1], masks[1]);
            matrixRound<0>(sv, eA0, eA1, rd, w, r0, r1, l,
                           colv[0], keysF[0], pivsF[0], masks[0]);
        } else {
            matrixRound<0>(sv, eA0, eA1, rd, w, r0, r1, l,
                           colv[0], keysF[0], pivsF[0], masks[0]);
            matrixRound<16>(sv, eB0, eB1, rd, w2, r0, r1, l,
                            colv[1], keysF[1], pivsF[1], masks[1]);
        }
        __syncthreads();
    }

    // ---- log|det| per matrix = sum log|piv_k| over write-once pivsF ----
    float lg = 0.0f;
    if (t < 256) {
        const int mat = t >> 7;             // waves 0-1: M1, waves 2-3: M2
        lg = __logf(fabsf(pivsF[mat][t & 127]));
#pragma unroll
        for (int off = 32; off > 0; off >>= 1)
            lg += __shfl_xor(lg, off, 64);
        if ((t & 63) == 0) redf[t >> 6] = lg;
    }
    __syncthreads();
    if (t == 0) out[bA] = redf[0] + redf[1];
    if (t == 1) out[bB] = redf[2] + redf[3];
}

extern "C" void kernel_launch(void* const* d_in, const int* in_sizes, int n_in,
                              void* d_out, int out_size, void* d_ws, size_t ws_size,
                              hipStream_t stream) {
    const float* rs = (const float*)d_in[0];
    const float* kp = (const float*)d_in[1];
    const float* cs = (const float*)d_in[2];
    const float* ss = (const float*)d_in[3];
    float* out = (float*)d_out;
    const int batch = in_sizes[0] / (NM * 3);  // 4096
    slater_logdet<<<dim3(batch / 2), dim3(NT), 0, stream>>>(rs, kp, cs, ss, out);
}